// Round 6
// baseline (559.704 us; speedup 1.0000x reference)
//
#include <hip/hip_runtime.h>
#include <hip/hip_bf16.h>

// LengthRegulator: out[b,t,:] = x[b, searchsorted_right(cum[b], t).clip(0,L-1), :]
//                  masked to 0 where t >= cum[b, L-1].
// B=32, L=1024, D=384, MAX_LEN=8192. fp32 in/out.
// Floor for OUR work: 403 MB nt-write + ~50 MB cold x read => ~75 us.
// dur_us carries ~330 us of harness poison-fill/restore (1.61 GB fills seen
// in rocprof at ~252 us each) we cannot touch.
//
// R6 = R4 structure (two kernels; fused scan in R5 regressed +23 us) with:
//  - copy kernel: NO LDS, NO barrier (idx loaded per-thread, L1 broadcast)
//  - 8 gather loads in flight per thread (full unroll), nt stores
//  - XCD swizzle: each XCD gets a contiguous 1024-t chunk per batch

#define B_FIXED 32
#define L_FIXED 1024
#define ROW_F4 96        // 384 floats / 4
#define RPB 32           // output rows per copy block

typedef float vfloat4 __attribute__((ext_vector_type(4)));

// Kernel A: per-batch inclusive scan of round(clip(dur,0)) in LDS, then
// searchsorted_right for all t in [0, max_len). idx = -1 where masked.
__global__ __launch_bounds__(1024) void lr_scan_idx_kernel(
    const float* __restrict__ durations, int* __restrict__ idx, int max_len) {
    __shared__ int s[L_FIXED];
    const int b = blockIdx.x;
    const int tid = threadIdx.x;
    float d = durations[b * L_FIXED + tid];
    s[tid] = (int)rintf(fmaxf(d, 0.0f));   // jnp.round = half-to-even = rintf
    __syncthreads();
    for (int off = 1; off < L_FIXED; off <<= 1) {
        int add = (tid >= off) ? s[tid - off] : 0;
        __syncthreads();
        s[tid] += add;
        __syncthreads();
    }
    const int total = s[L_FIXED - 1];
    for (int t = tid; t < max_len; t += 1024) {
        int lo = 0, hi = L_FIXED;
        while (lo < hi) {
            int mid = (lo + hi) >> 1;
            if (s[mid] <= t) lo = mid + 1; else hi = mid;
        }
        int v = min(lo, L_FIXED - 1);
        idx[b * max_len + t] = (t < total) ? v : -1;
    }
}

// Kernel B: streaming gather-copy. Block (96,4). Rows r = y + 4j, j=0..7.
// Per-j store region is contiguous: addr = obase + 384j + (y*96+x).
// No LDS, no barrier; 8 loads in flight; nontemporal stores.
__global__ __launch_bounds__(384) void lr_copy_kernel(
    const vfloat4* __restrict__ x, const int* __restrict__ idx,
    vfloat4* __restrict__ out, int max_len) {
    const int b = blockIdx.y;
    // XCD swizzle: consecutive dispatch slots (xb%8 -> XCD) map to far-apart
    // tiles so each XCD processes a contiguous 32-tile (1024-t) chunk.
    const int xb = blockIdx.x;
    const int tile = (xb & 7) * 32 + (xb >> 3);      // gridDim.x == 256
    const int t0 = tile * RPB;

    const int cx = threadIdx.x;
    const int y  = threadIdx.y;
    const long xbase = (long)b * L_FIXED * ROW_F4;
    const long obase = ((long)b * max_len + t0) * ROW_F4;
    const vfloat4 zero = {0.f, 0.f, 0.f, 0.f};
    const int* idx_b = idx + b * max_len + t0 + y;

    int row[8];
#pragma unroll
    for (int j = 0; j < 8; ++j) row[j] = idx_b[4 * j];   // L1 broadcast

    vfloat4 v[8];
#pragma unroll
    for (int j = 0; j < 8; ++j) {
        v[j] = zero;
        if (row[j] >= 0) v[j] = x[xbase + (long)row[j] * ROW_F4 + cx];
    }
#pragma unroll
    for (int j = 0; j < 8; ++j) {
        __builtin_nontemporal_store(
            v[j], &out[obase + (long)(y + 4 * j) * ROW_F4 + cx]);
    }
}

extern "C" void kernel_launch(void* const* d_in, const int* in_sizes, int n_in,
                              void* d_out, int out_size, void* d_ws, size_t ws_size,
                              hipStream_t stream) {
    const float* x = (const float*)d_in[0];          // (B, L, D) fp32
    const float* durations = (const float*)d_in[1];  // (B, L) fp32
    const int MAX_LEN = 8192;

    int* idx = (int*)d_ws;  // B * MAX_LEN ints = 1 MB scratch

    lr_scan_idx_kernel<<<B_FIXED, 1024, 0, stream>>>(durations, idx, MAX_LEN);

    dim3 grid(MAX_LEN / RPB, B_FIXED);               // (256, 32)
    dim3 block(96, 4);
    lr_copy_kernel<<<grid, block, 0, stream>>>(
        (const vfloat4*)x, idx, (vfloat4*)d_out, MAX_LEN);
}

// Round 7
// 483.850 us; speedup vs baseline: 1.1568x; 1.1568x over previous
//
#include <hip/hip_runtime.h>
#include <hip/hip_bf16.h>

// LengthRegulator: out[b,t,:] = x[b, searchsorted_right(cum[b], t).clip(0,L-1), :]
//                  masked to 0 where t >= cum[b, L-1].
// B=32, L=1024, D=384, MAX_LEN=8192. fp32 in/out.
// Floor for OUR work: 403 MB nt-write + ~50 MB cold x read => ~75 us.
// dur_us carries ~270 us of harness poison-fill/restore (1.61 GB fill ~252 us
// visible in rocprof) we cannot touch. R4 kernel-B share ~170 us (2.4 TB/s).
//
// R7 = R4 + ONE change (R5 fused scan regressed; R6 swizzle/no-LDS combo
// regressed badly): persistent copy kernel. 1024 blocks (all co-resident,
// 6144 waves <= 8192 capacity), each owns 8 consecutive 32-row tiles
// (384 KB contiguous stores), register-prefetches next tile's idx during
// current tile's gather+store. No LDS/barrier in the loop, no block churn.

#define B_FIXED 32
#define L_FIXED 1024
#define ROW_F4 96        // 384 floats / 4
#define RPB 32           // output rows per tile
#define TPB 8            // tiles per block

typedef float vfloat4 __attribute__((ext_vector_type(4)));

// Kernel A: per-batch inclusive scan of round(clip(dur,0)) in LDS, then
// searchsorted_right for all t in [0, max_len). idx = -1 where masked.
__global__ __launch_bounds__(1024) void lr_scan_idx_kernel(
    const float* __restrict__ durations, int* __restrict__ idx, int max_len) {
    __shared__ int s[L_FIXED];
    const int b = blockIdx.x;
    const int tid = threadIdx.x;
    float d = durations[b * L_FIXED + tid];
    s[tid] = (int)rintf(fmaxf(d, 0.0f));   // jnp.round = half-to-even = rintf
    __syncthreads();
    for (int off = 1; off < L_FIXED; off <<= 1) {
        int add = (tid >= off) ? s[tid - off] : 0;
        __syncthreads();
        s[tid] += add;
        __syncthreads();
    }
    const int total = s[L_FIXED - 1];
    for (int t = tid; t < max_len; t += 1024) {
        int lo = 0, hi = L_FIXED;
        while (lo < hi) {
            int mid = (lo + hi) >> 1;
            if (s[mid] <= t) lo = mid + 1; else hi = mid;
        }
        int v = min(lo, L_FIXED - 1);
        idx[b * max_len + t] = (t < total) ? v : -1;
    }
}

// Kernel B: persistent streaming gather-copy. Block (96,4); rows r = y+4j.
// Per-wave store bursts are contiguous 1 KB; idx prefetch overlaps stores.
__global__ __launch_bounds__(384) void lr_copy_kernel(
    const vfloat4* __restrict__ x, const int* __restrict__ idx,
    vfloat4* __restrict__ out, int max_len) {
    const int b = blockIdx.y;
    const int t_base = blockIdx.x * (RPB * TPB);     // 256 rows per block
    const int cx = threadIdx.x;
    const int y  = threadIdx.y;
    const long xbase = (long)b * L_FIXED * ROW_F4;
    const vfloat4 zero = {0.f, 0.f, 0.f, 0.f};
    const int* idx_p = idx + b * max_len;

    int row[8];
#pragma unroll
    for (int j = 0; j < 8; ++j) row[j] = idx_p[t_base + y + 4 * j];

    for (int n = 0; n < TPB; ++n) {
        const int t0 = t_base + n * RPB;
        // Gather current tile (8 loads in flight).
        vfloat4 v[8];
#pragma unroll
        for (int j = 0; j < 8; ++j) {
            v[j] = zero;
            if (row[j] >= 0) v[j] = x[xbase + (long)row[j] * ROW_F4 + cx];
        }
        // Prefetch next tile's idx (overlaps with gather latency + stores).
        int nrow[8];
        if (n + 1 < TPB) {
#pragma unroll
            for (int j = 0; j < 8; ++j)
                nrow[j] = idx_p[t0 + RPB + y + 4 * j];
        }
        // Store current tile.
        const long obase = ((long)b * max_len + t0) * ROW_F4;
#pragma unroll
        for (int j = 0; j < 8; ++j)
            __builtin_nontemporal_store(
                v[j], &out[obase + (long)(y + 4 * j) * ROW_F4 + cx]);
#pragma unroll
        for (int j = 0; j < 8; ++j) row[j] = nrow[j];
    }
}

extern "C" void kernel_launch(void* const* d_in, const int* in_sizes, int n_in,
                              void* d_out, int out_size, void* d_ws, size_t ws_size,
                              hipStream_t stream) {
    const float* x = (const float*)d_in[0];          // (B, L, D) fp32
    const float* durations = (const float*)d_in[1];  // (B, L) fp32
    const int MAX_LEN = 8192;

    int* idx = (int*)d_ws;  // B * MAX_LEN ints = 1 MB scratch

    lr_scan_idx_kernel<<<B_FIXED, 1024, 0, stream>>>(durations, idx, MAX_LEN);

    dim3 grid(MAX_LEN / (RPB * TPB), B_FIXED);       // (32, 32) = 1024 blocks
    dim3 block(96, 4);
    lr_copy_kernel<<<grid, block, 0, stream>>>(
        (const vfloat4*)x, idx, (vfloat4*)d_out, MAX_LEN);
}

// Round 8
// 436.685 us; speedup vs baseline: 1.2817x; 1.1080x over previous
//
#include <hip/hip_runtime.h>
#include <hip/hip_bf16.h>

// LengthRegulator: out[b,t,:] = x[b, searchsorted_right(cum[b], t).clip(0,L-1), :]
//                  masked to 0 where t >= cum[b, L-1].
// B=32, L=1024, D=384, MAX_LEN=8192. fp32 in/out.
// Floor for OUR work: 403 MB nt-write + ~50 MB cold x read => ~70-75 us.
// dur_us carries ~330-350 us of harness poison/restore (1.61 GB ws fill
// ~252 us + 403 MB out fill ~64 us + d_in restore) we cannot touch.
//
// Best known: R4 (439 us) = 8192 small copy blocks, LDS idx stage, 2-deep
// unroll, nt stores. R5 fused (+23), R6 no-LDS/8-deep/swizzle (+120),
// R7 persistent (+45) all regressed -> max block-parallelism + short chains.
//
// R8 = R4 + ONE change: kernel A scan 20 barriers -> 3 (shfl wave-scan +
// wave0 scan of 16 wave sums). Kernel B identical to R4.

#define B_FIXED 32
#define L_FIXED 1024
#define ROW_F4 96        // 384 floats / 4
#define RPB 32           // output rows per copy block

typedef float vfloat4 __attribute__((ext_vector_type(4)));

// Kernel A: per-batch inclusive scan of round(clip(dur,0)), then
// searchsorted_right for all t in [0, max_len). idx = -1 where masked.
__global__ __launch_bounds__(1024) void lr_scan_idx_kernel(
    const float* __restrict__ durations, int* __restrict__ idx, int max_len) {
    __shared__ int s[L_FIXED];
    __shared__ int wsum[16];
    const int b = blockIdx.x;
    const int tid = threadIdx.x;
    const int lane = tid & 63;
    const int wid = tid >> 6;          // 16 waves

    int v = (int)rintf(fmaxf(durations[b * L_FIXED + tid], 0.0f));

    // Inclusive wave scan via shfl_up (no LDS, no barriers).
    int sc = v;
#pragma unroll
    for (int off = 1; off < 64; off <<= 1) {
        int n = __shfl_up(sc, off, 64);
        if (lane >= off) sc += n;
    }
    if (lane == 63) wsum[wid] = sc;
    __syncthreads();

    // Wave 0 scans the 16 wave sums.
    if (tid < 16) {
        int w = wsum[tid];
#pragma unroll
        for (int off = 1; off < 16; off <<= 1) {
            int n = __shfl_up(w, off, 64);
            if (tid >= off) w += n;
        }
        wsum[tid] = w;                 // inclusive wave-sum scan
    }
    __syncthreads();

    s[tid] = sc + ((wid > 0) ? wsum[wid - 1] : 0);
    __syncthreads();

    const int total = s[L_FIXED - 1];
    for (int t = tid; t < max_len; t += 1024) {
        int lo = 0, hi = L_FIXED;
        while (lo < hi) {
            int mid = (lo + hi) >> 1;
            if (s[mid] <= t) lo = mid + 1; else hi = mid;
        }
        int r = min(lo, L_FIXED - 1);
        idx[b * max_len + t] = (t < total) ? r : -1;
    }
}

// Kernel B: streaming gather-copy (identical to R4). Block (96,4);
// LDS idx stage; 2 rows in flight; nontemporal stores.
__global__ __launch_bounds__(384) void lr_copy_kernel(
    const vfloat4* __restrict__ x, const int* __restrict__ idx,
    vfloat4* __restrict__ out, int max_len) {
    __shared__ int s_idx[RPB];
    const int b = blockIdx.y;
    const int t0 = blockIdx.x * RPB;
    const int lin = threadIdx.y * 96 + threadIdx.x;
    if (lin < RPB) s_idx[lin] = idx[b * max_len + t0 + lin];
    __syncthreads();

    const long xbase = (long)b * L_FIXED * ROW_F4;
    const long obase = ((long)b * max_len + t0) * ROW_F4;
    const int cx = threadIdx.x;
    const int y  = threadIdx.y;
    const vfloat4 zero = {0.f, 0.f, 0.f, 0.f};

#pragma unroll
    for (int k = 0; k < 4; ++k) {
        const int ra = y + 8 * k;
        const int rb = ra + 4;
        const int rowa = s_idx[ra];
        const int rowb = s_idx[rb];
        vfloat4 va = zero, vb = zero;
        if (rowa >= 0) va = x[xbase + (long)rowa * ROW_F4 + cx];
        if (rowb >= 0) vb = x[xbase + (long)rowb * ROW_F4 + cx];
        __builtin_nontemporal_store(va, &out[obase + (long)ra * ROW_F4 + cx]);
        __builtin_nontemporal_store(vb, &out[obase + (long)rb * ROW_F4 + cx]);
    }
}

extern "C" void kernel_launch(void* const* d_in, const int* in_sizes, int n_in,
                              void* d_out, int out_size, void* d_ws, size_t ws_size,
                              hipStream_t stream) {
    const float* x = (const float*)d_in[0];          // (B, L, D) fp32
    const float* durations = (const float*)d_in[1];  // (B, L) fp32
    const int MAX_LEN = 8192;

    int* idx = (int*)d_ws;  // B * MAX_LEN ints = 1 MB scratch

    lr_scan_idx_kernel<<<B_FIXED, 1024, 0, stream>>>(durations, idx, MAX_LEN);

    dim3 grid(MAX_LEN / RPB, B_FIXED);               // (256, 32)
    dim3 block(96, 4);
    lr_copy_kernel<<<grid, block, 0, stream>>>(
        (const vfloat4*)x, idx, (vfloat4*)d_out, MAX_LEN);
}